// Round 8
// baseline (335.119 us; speedup 1.0000x reference)
//
#include <hip/hip_runtime.h>
#include <math.h>

#define EPS 1e-5f
#define N0 1000
#define NK1 500
#define NK2 100
#define NE 32000
#define NBLK 64
#define NSYNC 4
#define FPSCALE 16777216.0f   // 2^24 fixed-point for deterministic scatter

// module-load zero-initialized; monotone across graph replays (epoch scheme)
__device__ unsigned g_bar = 0u;
__device__ unsigned g_epoch = 0u;

__device__ __forceinline__ float bnr(float h, float sc, float sh) {
    float v = fmaf(h, sc, sh);
    return v > 0.f ? v : 0.f;
}
// relaxed agent-scope atomics: bypass non-coherent L1/L2, hit coherence point
__device__ __forceinline__ float aload(const float* p) {
    return __hip_atomic_load(p, __ATOMIC_RELAXED, __HIP_MEMORY_SCOPE_AGENT);
}
__device__ __forceinline__ void astore(float* p, float v) {
    __hip_atomic_store(p, v, __ATOMIC_RELAXED, __HIP_MEMORY_SCOPE_AGENT);
}
__device__ __forceinline__ int aiload(const int* p) {
    return __hip_atomic_load(p, __ATOMIC_RELAXED, __HIP_MEMORY_SCOPE_AGENT);
}
__device__ __forceinline__ void aistore(int* p, int v) {
    __hip_atomic_store(p, v, __ATOMIC_RELAXED, __HIP_MEMORY_SCOPE_AGENT);
}

// fence-free grid barrier on monotone counter; epoch bump at last arrival of
// the final barrier makes the kernel replay-safe with no reset dispatch.
__device__ __forceinline__ void gsync(unsigned base, unsigned k, bool spin) {
    asm volatile("s_waitcnt vmcnt(0) lgkmcnt(0)" ::: "memory");
    __syncthreads();
    if (threadIdx.x == 0) {
        unsigned ret = __hip_atomic_fetch_add(&g_bar, 1u, __ATOMIC_RELAXED, __HIP_MEMORY_SCOPE_AGENT);
        if (k == NSYNC && ret == base + NSYNC * NBLK - 1u)
            __hip_atomic_store(&g_epoch, base / (NSYNC * NBLK) + 1u,
                               __ATOMIC_RELAXED, __HIP_MEMORY_SCOPE_AGENT);
        if (spin) {
            unsigned target = base + k * NBLK;
            unsigned spins = 0;
            while (__hip_atomic_load(&g_bar, __ATOMIC_RELAXED, __HIP_MEMORY_SCOPE_AGENT) < target) {
                if (++spins > (1u << 22)) break;  // hang safety
                __builtin_amdgcn_s_sleep(1);
            }
        }
    }
    __syncthreads();
}

struct Args {
    const float *x; const int *ei; const float *ea;
    const float *w0, *b0, *g0, *be0;
    const float *w1, *b1, *g1, *be1;
    const float *w2a, *b2a, *g2a, *be2a;
    const float *w2b, *b2b, *g2b, *be2b;
    const float *w3a, *b3a, *w3b, *b3b;
    const float *p1_wrel, *p1_wroot, *p1_b, *p2_wrel, *p2_wroot, *p2_b;
    float *h1, *psum1, *xp1, *h2a, *psum2a, *h2b, *psum2b;
    int *rk_g, *nsrc, *ndst; float *new_ew;
    float *out;
};

__global__ __launch_bounds__(256) void k_mega(Args a) {
    union __align__(16) SMem {
        struct { float xs[16][68], wsm[64][65], rs[256], rq[256], sc0[64], sh0[64]; } A;
        struct { float ss[N0], tt[N0]; unsigned long long acc64[N0];
                 float rs[256], rq[256], sc[64], sh[64], wr[64], wo[64]; } B;
        struct { float xs[8][68], wsm[128][65], rs[256], rq[256]; } C;
        struct { float wsm[200][33], xs[8][36], sc[128], sh[128], rs[256], rq[256]; } D;
        struct { float ss[NK1], tt[NK1]; unsigned long long acc64[NK1];
                 float sc[200], sh[200], wr[200], wo[200], g[200], h3[128], o[2];
                 int pn[NK2]; float th[NK2]; } E;
    };
    __shared__ SMem sm;
    __shared__ unsigned sh_base;
    const int b = blockIdx.x, t = threadIdx.x;
    const int lane = t & 63, wv = t >> 6;

    if (t == 0)
        sh_base = __hip_atomic_load(&g_epoch, __ATOMIC_RELAXED, __HIP_MEMORY_SCOPE_AGENT) * (NSYNC * NBLK);
    __syncthreads();
    const unsigned base = sh_base;

    // ================= P1: lin0+lin1 (64 blocks x 16-node tiles) =============
    {
        const int nb = b * 16;
        // redundant BN0 stats (cheap VALU scan of x, cached reads)
        {
            const int c = lane, slot = wv;
            float wa = a.w0[c * 3], wb = a.w0[c * 3 + 1], wc = a.w0[c * 3 + 2], bb = a.b0[c];
            float s = 0.f, q = 0.f;
            for (int n = slot; n < N0; n += 4) {
                float h = fmaf(wa, a.x[n * 3], fmaf(wb, a.x[n * 3 + 1], fmaf(wc, a.x[n * 3 + 2], bb)));
                s += h; q += h * h;
            }
            sm.A.rs[t] = s; sm.A.rq[t] = q;
            __syncthreads();
            if (t < 64) {
                float S = sm.A.rs[t] + sm.A.rs[t + 64] + sm.A.rs[t + 128] + sm.A.rs[t + 192];
                float Q = sm.A.rq[t] + sm.A.rq[t + 64] + sm.A.rq[t + 128] + sm.A.rq[t + 192];
                float mu = S * (1.f / N0);
                float var = Q * (1.f / N0) - mu * mu;
                float sv = a.g0[t] * rsqrtf(var + EPS);
                sm.A.sc0[t] = sv; sm.A.sh0[t] = a.be0[t] - mu * sv;
            }
            __syncthreads();
        }
        // stage y0 tile (recompute) + w1
        for (int i = 0; i < 4; ++i) {
            int e = t + i * 256;
            int r = e >> 6, cc = e & 63;
            int n = nb + r;
            float v = 0.f;
            if (n < N0) {
                float h = fmaf(a.w0[cc * 3], a.x[n * 3],
                          fmaf(a.w0[cc * 3 + 1], a.x[n * 3 + 1],
                          fmaf(a.w0[cc * 3 + 2], a.x[n * 3 + 2], a.b0[cc])));
                v = bnr(h, sm.A.sc0[cc], sm.A.sh0[cc]);
            }
            sm.A.xs[r][cc] = v;
        }
        for (int i = 0; i < 16; ++i) {
            int e = t + i * 256;
            sm.A.wsm[e >> 6][e & 63] = a.w1[e];
        }
        __syncthreads();
        const int c = lane, slot = wv;
        const int r0 = slot * 4;
        float bb1 = a.b1[c];
        float a0 = bb1, a1 = bb1, a2 = bb1, a3 = bb1;
        #pragma unroll
        for (int kq = 0; kq < 16; ++kq) {
            float w0v = sm.A.wsm[c][4 * kq],     w1v = sm.A.wsm[c][4 * kq + 1];
            float w2v = sm.A.wsm[c][4 * kq + 2], w3v = sm.A.wsm[c][4 * kq + 3];
            float4 x0 = *(const float4*)&sm.A.xs[r0 + 0][4 * kq];
            float4 x1 = *(const float4*)&sm.A.xs[r0 + 1][4 * kq];
            float4 x2 = *(const float4*)&sm.A.xs[r0 + 2][4 * kq];
            float4 x3 = *(const float4*)&sm.A.xs[r0 + 3][4 * kq];
            a0 = fmaf(x0.x, w0v, fmaf(x0.y, w1v, fmaf(x0.z, w2v, fmaf(x0.w, w3v, a0))));
            a1 = fmaf(x1.x, w0v, fmaf(x1.y, w1v, fmaf(x1.z, w2v, fmaf(x1.w, w3v, a1))));
            a2 = fmaf(x2.x, w0v, fmaf(x2.y, w1v, fmaf(x2.z, w2v, fmaf(x2.w, w3v, a2))));
            a3 = fmaf(x3.x, w0v, fmaf(x3.y, w1v, fmaf(x3.z, w2v, fmaf(x3.w, w3v, a3))));
        }
        float av[4] = {a0, a1, a2, a3};
        float sacc = 0.f, qacc = 0.f;
        #pragma unroll
        for (int i = 0; i < 4; ++i) {
            int n = nb + r0 + i;
            if (n < N0) {
                astore(&a.h1[n * 64 + c], av[i]);
                sacc += av[i]; qacc += av[i] * av[i];
            }
        }
        __syncthreads();
        sm.A.rs[t] = sacc; sm.A.rq[t] = qacc;
        __syncthreads();
        if (t < 64) {
            astore(&a.psum1[b * 128 + t],
                   sm.A.rs[t] + sm.A.rs[t + 64] + sm.A.rs[t + 128] + sm.A.rs[t + 192]);
            astore(&a.psum1[b * 128 + 64 + t],
                   sm.A.rq[t] + sm.A.rq[t + 64] + sm.A.rq[t + 128] + sm.A.rq[t + 192]);
        }
    }
    gsync(base, 1, true);

    // ====== P2: per-block redundant {BN1, t1-all, scatter-all}; distributed
    //            rank+select (16 nodes/block). Deterministic via int64 LDS. ===
    {
        // BN1 partial reduce (4 parts x 16 blocks) + zero acc64 + stage wrel/wroot
        {
            const int ch = t & 63, part = t >> 6;
            float s = 0.f, q = 0.f;
            for (int i = 0; i < 16; ++i) {
                int blk = part * 16 + i;
                s += aload(&a.psum1[blk * 128 + ch]);
                q += aload(&a.psum1[blk * 128 + 64 + ch]);
            }
            sm.B.rs[t] = s; sm.B.rq[t] = q;
        }
        for (int i = t; i < N0; i += 256) sm.B.acc64[i] = 0ull;
        if (t < 64) { sm.B.wr[t] = a.p1_wrel[t]; sm.B.wo[t] = a.p1_wroot[t]; }
        __syncthreads();
        if (t < 64) {
            float S = sm.B.rs[t] + sm.B.rs[t + 64] + sm.B.rs[t + 128] + sm.B.rs[t + 192];
            float Q = sm.B.rq[t] + sm.B.rq[t + 64] + sm.B.rq[t + 128] + sm.B.rq[t + 192];
            float mu = S * (1.f / N0);
            float var = Q * (1.f / N0) - mu * mu;
            float sv = a.g1[t] * rsqrtf(var + EPS);
            sm.B.sc[t] = sv; sm.B.sh[t] = a.be1[t] - mu * sv;
        }
        __syncthreads();

        // t1-all: 4-lane groups, 16 channels each; preload coeffs to regs
        {
            const int sub = t & 3, grp = t >> 2;
            float wrv[16], wov[16], scv[16], shv[16];
            #pragma unroll
            for (int i = 0; i < 16; ++i) {
                int ch = sub * 16 + i;
                wrv[i] = sm.B.wr[ch]; wov[i] = sm.B.wo[ch];
                scv[i] = sm.B.sc[ch]; shv[i] = sm.B.sh[ch];
            }
            float pb = a.p1_b[0];
            for (int p = 0; p < 16; ++p) {
                int n = p * 64 + grp;
                if (n < N0) {
                    float dr = 0.f, dt = 0.f;
                    #pragma unroll
                    for (int i = 0; i < 16; ++i) {
                        float v = bnr(aload(&a.h1[n * 64 + sub * 16 + i]), scv[i], shv[i]);
                        dr = fmaf(v, wrv[i], dr);
                        dt = fmaf(v, wov[i], dt);
                    }
                    dr += __shfl_xor(dr, 1, 64); dr += __shfl_xor(dr, 2, 64);
                    dt += __shfl_xor(dt, 1, 64); dt += __shfl_xor(dt, 2, 64);
                    if (sub == 0) { sm.B.tt[n] = dr; sm.B.ss[n] = dt + pb; }
                }
            }
        }
        __syncthreads();

        // scatter-all (int64 fixed point -> bit-identical across blocks)
        for (int e = t; e < NE; e += 256) {
            float w = a.ea[e];
            if (w != 0.f) {
                float c = w * sm.B.tt[a.ei[e]];
                long long ll = __float2ll_rn(c * FPSCALE);
                atomicAdd((unsigned long long*)&sm.B.acc64[a.ei[NE + e]],
                          (unsigned long long)ll);
            }
        }
        __syncthreads();
        for (int i = t; i < N0; i += 256)
            sm.B.ss[i] += (float)((double)(long long)sm.B.acc64[i] * (1.0 / (double)FPSCALE));
        __syncthreads();

        // rank + select own 16 nodes (wave-per-node)
        for (int it = 0; it < 4; ++it) {
            int n = b * 16 + it * 4 + wv;
            if (n < N0) {
                float s = sm.B.ss[n];
                int r = 0;
                for (int m = lane; m < N0; m += 64) {
                    float smv = sm.B.ss[m];
                    r += (smv > s) || (smv == s && m < n);
                }
                #pragma unroll
                for (int msk = 32; msk >= 1; msk >>= 1) r += __shfl_xor(r, msk, 64);
                if (lane == 0) aistore(&a.rk_g[n], r);
                if (r < NK1) {
                    float tn = tanhf(s);
                    astore(&a.xp1[r * 64 + lane],
                           bnr(aload(&a.h1[n * 64 + lane]), sm.B.sc[lane], sm.B.sh[lane]) * tn);
                }
            }
        }
    }
    gsync(base, 2, true);

    // ====== P3: lin2a (8 rows/block) + edge remap (500 edges/block) ==========
    {
        const int nb = b * 8;
        const int nrows = (NK1 - nb) < 8 ? ((NK1 - nb) > 0 ? (NK1 - nb) : 0) : 8;
        // remap own slice
        for (int e = b * 500 + t; e < b * 500 + 500; e += 256) {
            int s_ = a.ei[e], d_ = a.ei[NE + e];
            int rs_ = aiload(&a.rk_g[s_]), rd_ = aiload(&a.rk_g[d_]);
            bool v = (rs_ < NK1) && (rd_ < NK1);
            aistore(&a.nsrc[e], v ? rs_ : 0);
            aistore(&a.ndst[e], v ? rd_ : 0);
            astore(&a.new_ew[e], v ? a.ea[e] : 0.f);
        }
        // stage xp1 rows + w2a
        for (int i = 0; i < 2; ++i) {
            int e = t + i * 256;
            int r = e >> 6, cc = e & 63;
            sm.C.xs[r][cc] = (r < nrows) ? aload(&a.xp1[(nb + r) * 64 + cc]) : 0.f;
        }
        for (int i = 0; i < 32; ++i) {
            int e = t + i * 256;
            sm.C.wsm[e >> 6][e & 63] = a.w2a[e];
        }
        __syncthreads();
        const int c = t & 127, half = t >> 7;
        const int r0 = half * 4;
        float bb2 = a.b2a[c];
        float a0 = bb2, a1 = bb2, a2 = bb2, a3 = bb2;
        #pragma unroll
        for (int kq = 0; kq < 16; ++kq) {
            float w0v = sm.C.wsm[c][4 * kq],     w1v = sm.C.wsm[c][4 * kq + 1];
            float w2v = sm.C.wsm[c][4 * kq + 2], w3v = sm.C.wsm[c][4 * kq + 3];
            float4 x0 = *(const float4*)&sm.C.xs[r0 + 0][4 * kq];
            float4 x1 = *(const float4*)&sm.C.xs[r0 + 1][4 * kq];
            float4 x2 = *(const float4*)&sm.C.xs[r0 + 2][4 * kq];
            float4 x3 = *(const float4*)&sm.C.xs[r0 + 3][4 * kq];
            a0 = fmaf(x0.x, w0v, fmaf(x0.y, w1v, fmaf(x0.z, w2v, fmaf(x0.w, w3v, a0))));
            a1 = fmaf(x1.x, w0v, fmaf(x1.y, w1v, fmaf(x1.z, w2v, fmaf(x1.w, w3v, a1))));
            a2 = fmaf(x2.x, w0v, fmaf(x2.y, w1v, fmaf(x2.z, w2v, fmaf(x2.w, w3v, a2))));
            a3 = fmaf(x3.x, w0v, fmaf(x3.y, w1v, fmaf(x3.z, w2v, fmaf(x3.w, w3v, a3))));
        }
        float av[4] = {a0, a1, a2, a3};
        float sacc = 0.f, qacc = 0.f;
        #pragma unroll
        for (int i = 0; i < 4; ++i) {
            int r = r0 + i;
            if (r < nrows) {
                astore(&a.h2a[(nb + r) * 128 + c], av[i]);
                sacc += av[i]; qacc += av[i] * av[i];
            }
        }
        __syncthreads();
        sm.C.rs[t] = sacc; sm.C.rq[t] = qacc;
        __syncthreads();
        if (t < 128) {
            astore(&a.psum2a[b * 256 + t],       sm.C.rs[t] + sm.C.rs[t + 128]);
            astore(&a.psum2a[b * 256 + 128 + t], sm.C.rq[t] + sm.C.rq[t + 128]);
        }
    }
    gsync(base, 3, true);

    // ====== P4: lin2b (8 rows/block, k-tiled) ================================
    {
        const int nb = b * 8;
        const int nrows = (NK1 - nb) < 8 ? ((NK1 - nb) > 0 ? (NK1 - nb) : 0) : 8;
        {
            const int ch = t & 127, half = t >> 7;
            float s = 0.f, q = 0.f;
            for (int i = 0; i < 32; ++i) {
                int blk = half * 32 + i;
                s += aload(&a.psum2a[blk * 256 + ch]);
                q += aload(&a.psum2a[blk * 256 + 128 + ch]);
            }
            sm.D.rs[t] = s; sm.D.rq[t] = q;
        }
        __syncthreads();
        if (t < 128) {
            float S = sm.D.rs[t] + sm.D.rs[t + 128];
            float Q = sm.D.rq[t] + sm.D.rq[t + 128];
            float mu = S * (1.f / NK1);
            float var = Q * (1.f / NK1) - mu * mu;
            float sv = a.g2a[t] * rsqrtf(var + EPS);
            sm.D.sc[t] = sv; sm.D.sh[t] = a.be2a[t] - mu * sv;
        }
        float acc[8];
        float bb = (t < 200) ? a.b2b[t] : 0.f;
        #pragma unroll
        for (int r = 0; r < 8; ++r) acc[r] = bb;
        for (int kt = 0; kt < 4; ++kt) {
            int k0 = kt * 32;
            __syncthreads();
            for (int i = 0; i < 25; ++i) {
                int e = t + i * 256;
                int r = e >> 5, k = e & 31;
                sm.D.wsm[r][k] = a.w2b[r * 128 + k0 + k];
            }
            {
                int r = t >> 5, k = t & 31;
                sm.D.xs[r][k] = (r < nrows)
                    ? bnr(aload(&a.h2a[(nb + r) * 128 + k0 + k]), sm.D.sc[k0 + k], sm.D.sh[k0 + k])
                    : 0.f;
            }
            __syncthreads();
            if (t < 200) {
                #pragma unroll
                for (int kq = 0; kq < 8; ++kq) {
                    float w0v = sm.D.wsm[t][4 * kq],     w1v = sm.D.wsm[t][4 * kq + 1];
                    float w2v = sm.D.wsm[t][4 * kq + 2], w3v = sm.D.wsm[t][4 * kq + 3];
                    #pragma unroll
                    for (int r = 0; r < 8; ++r) {
                        float4 xv = *(const float4*)&sm.D.xs[r][4 * kq];
                        acc[r] = fmaf(xv.x, w0v, fmaf(xv.y, w1v, fmaf(xv.z, w2v, fmaf(xv.w, w3v, acc[r]))));
                    }
                }
            }
        }
        if (t < 200) {
            float s = 0.f, q = 0.f;
            #pragma unroll
            for (int r = 0; r < 8; ++r) {
                if (r < nrows) {
                    astore(&a.h2b[(nb + r) * 200 + t], acc[r]);
                    s += acc[r]; q += acc[r] * acc[r];
                }
            }
            astore(&a.psum2b[b * 400 + t], s);
            astore(&a.psum2b[b * 400 + 200 + t], q);
        }
    }
    gsync(base, 4, b == 0);  // non-zero blocks arrive and exit

    // ====== P5 (block 0): BN2b, score2, scatter2, rank2, select, maxpool,
    //                      mlp_third, log_softmax ============================
    if (b == 0) {
        if (t < 200) {
            float s = 0.f, q = 0.f;
            for (int i = 0; i < 64; ++i) {
                s += aload(&a.psum2b[i * 400 + t]);
                q += aload(&a.psum2b[i * 400 + 200 + t]);
            }
            float mu = s * (1.f / NK1);
            float var = q * (1.f / NK1) - mu * mu;
            float sv = a.g2b[t] * rsqrtf(var + EPS);
            sm.E.sc[t] = sv; sm.E.sh[t] = a.be2b[t] - mu * sv;
            sm.E.wr[t] = a.p2_wrel[t]; sm.E.wo[t] = a.p2_wroot[t];
        }
        for (int i = t; i < NK1; i += 256) sm.E.acc64[i] = 0ull;
        __syncthreads();

        // score2: 4-lane groups, 50 channels each
        {
            const int sub = t & 3, grp = t >> 2;
            float pb2 = a.p2_b[0];
            for (int p = 0; p < 8; ++p) {
                int n = p * 64 + grp;
                if (n < NK1) {
                    float dr = 0.f, dt = 0.f;
                    for (int i = 0; i < 50; ++i) {
                        int ch = sub * 50 + i;
                        float v = bnr(aload(&a.h2b[n * 200 + ch]), sm.E.sc[ch], sm.E.sh[ch]);
                        dr = fmaf(v, sm.E.wr[ch], dr);
                        dt = fmaf(v, sm.E.wo[ch], dt);
                    }
                    dr += __shfl_xor(dr, 1, 64); dr += __shfl_xor(dr, 2, 64);
                    dt += __shfl_xor(dt, 1, 64); dt += __shfl_xor(dt, 2, 64);
                    if (sub == 0) { sm.E.tt[n] = dr; sm.E.ss[n] = dt + pb2; }
                }
            }
        }
        __syncthreads();

        // scatter2
        for (int e = t; e < NE; e += 256) {
            float w = aload(&a.new_ew[e]);
            if (w != 0.f) {
                float c = w * sm.E.tt[aiload(&a.nsrc[e])];
                long long ll = __float2ll_rn(c * FPSCALE);
                atomicAdd((unsigned long long*)&sm.E.acc64[aiload(&a.ndst[e])],
                          (unsigned long long)ll);
            }
        }
        __syncthreads();
        for (int i = t; i < NK1; i += 256)
            sm.E.ss[i] += (float)((double)(long long)sm.E.acc64[i] * (1.0 / (double)FPSCALE));
        __syncthreads();

        // rank2 (thread-per-node x2, broadcast scan) + capture top-100
        if (t < 250) {
            #pragma unroll
            for (int h = 0; h < 2; ++h) {
                int n = t + h * 250;
                float s = sm.E.ss[n];
                int r = 0;
                for (int m = 0; m < NK1; ++m) {
                    float smv = sm.E.ss[m];
                    r += (smv > s) || (smv == s && m < n);
                }
                if (r < NK2) { sm.E.pn[r] = n; sm.E.th[r] = tanhf(s); }
            }
        }
        __syncthreads();

        // global max pool over 100 selected scaled rows
        if (t < 200) {
            float m = -1e30f;
            for (int j = 0; j < NK2; ++j) {
                float v = bnr(aload(&a.h2b[sm.E.pn[j] * 200 + t]), sm.E.sc[t], sm.E.sh[t]) * sm.E.th[j];
                m = fmaxf(m, v);
            }
            sm.E.g[t] = m;
        }
        __syncthreads();

        // h3 = relu(w3a @ g + b3a), wave-per-output
        for (int i = 0; i < 32; ++i) {
            int r = wv + 4 * i;
            float p = 0.f;
            #pragma unroll
            for (int j = 0; j < 4; ++j) {
                int ch = lane + 64 * j;
                if (ch < 200) p = fmaf(a.w3a[r * 200 + ch], sm.E.g[ch], p);
            }
            #pragma unroll
            for (int m = 32; m >= 1; m >>= 1) p += __shfl_xor(p, m, 64);
            if (lane == 0) sm.E.h3[r] = fmaxf(p + a.b3a[r], 0.f);
        }
        __syncthreads();
        if (t < 128) {
            int ow = t >> 6;
            float p = a.w3b[ow * 128 + lane] * sm.E.h3[lane]
                    + a.w3b[ow * 128 + 64 + lane] * sm.E.h3[64 + lane];
            #pragma unroll
            for (int m = 32; m >= 1; m >>= 1) p += __shfl_xor(p, m, 64);
            if (lane == 0) sm.E.o[ow] = fmaxf(p + a.b3b[ow], 0.f);
        }
        __syncthreads();
        if (t == 0) {
            float m = fmaxf(sm.E.o[0], sm.E.o[1]);
            float l = m + logf(expf(sm.E.o[0] - m) + expf(sm.E.o[1] - m));
            a.out[0] = sm.E.o[0] - l;
            a.out[1] = sm.E.o[1] - l;
        }
    }
}

extern "C" void kernel_launch(void* const* d_in, const int* in_sizes, int n_in,
                              void* d_out, int out_size, void* d_ws, size_t ws_size,
                              hipStream_t stream) {
    float* ws = (float*)d_ws;

    Args a;
    a.x    = (const float*)d_in[0];
    a.ei   = (const int*)d_in[1];
    a.ea   = (const float*)d_in[2];
    a.w0   = (const float*)d_in[3];  a.b0   = (const float*)d_in[4];
    a.g0   = (const float*)d_in[5];  a.be0  = (const float*)d_in[6];
    a.w1   = (const float*)d_in[7];  a.b1   = (const float*)d_in[8];
    a.g1   = (const float*)d_in[9];  a.be1  = (const float*)d_in[10];
    a.w2a  = (const float*)d_in[11]; a.b2a  = (const float*)d_in[12];
    a.g2a  = (const float*)d_in[13]; a.be2a = (const float*)d_in[14];
    a.w2b  = (const float*)d_in[15]; a.b2b  = (const float*)d_in[16];
    a.g2b  = (const float*)d_in[17]; a.be2b = (const float*)d_in[18];
    a.w3a  = (const float*)d_in[19]; a.b3a  = (const float*)d_in[20];
    a.w3b  = (const float*)d_in[21]; a.b3b  = (const float*)d_in[22];
    a.p1_wrel  = (const float*)d_in[23];
    a.p1_wroot = (const float*)d_in[24];
    a.p1_b     = (const float*)d_in[25];
    a.p2_wrel  = (const float*)d_in[26];
    a.p2_wroot = (const float*)d_in[27];
    a.p2_b     = (const float*)d_in[28];

    a.h1     = ws;                      // 64000
    a.psum1  = ws + 64000;              // 8192   (64 x 128)
    a.xp1    = ws + 72192;              // 32000
    a.rk_g   = (int*)(ws + 104192);     // 1000
    a.h2a    = ws + 105192;             // 64000
    a.psum2a = ws + 169192;             // 16384  (64 x 256)
    a.h2b    = ws + 185576;             // 100000
    a.psum2b = ws + 285576;             // 25600  (64 x 400)
    a.nsrc   = (int*)(ws + 311176);     // 32000
    a.ndst   = (int*)(ws + 343176);     // 32000
    a.new_ew = ws + 375176;             // 32000
    a.out    = (float*)d_out;

    k_mega<<<NBLK, 256, 0, stream>>>(a);
}

// Round 9
// 130.200 us; speedup vs baseline: 2.5739x; 2.5739x over previous
//
#include <hip/hip_runtime.h>
#include <math.h>

#define EPS 1e-5f
#define N0 1000
#define NK1 500
#define NK2 100
#define NE 32000
#define NBLK 64
#define NT 16
#define NSYNC 8

// module-load zero-initialized; monotone across graph replays
__device__ unsigned g_bar = 0u;
__device__ unsigned g_epoch = 0u;

__device__ __forceinline__ float bnr(float h, float sc, float sh) {
    float v = fmaf(h, sc, sh);
    return v > 0.f ? v : 0.f;
}
// relaxed agent-scope atomics: bypass non-coherent L1/L2, hit coherence point
__device__ __forceinline__ float aload(const float* p) {
    return __hip_atomic_load(p, __ATOMIC_RELAXED, __HIP_MEMORY_SCOPE_AGENT);
}
__device__ __forceinline__ void astore(float* p, float v) {
    __hip_atomic_store(p, v, __ATOMIC_RELAXED, __HIP_MEMORY_SCOPE_AGENT);
}
__device__ __forceinline__ int aiload(const int* p) {
    return __hip_atomic_load(p, __ATOMIC_RELAXED, __HIP_MEMORY_SCOPE_AGENT);
}
__device__ __forceinline__ void aistore(int* p, int v) {
    __hip_atomic_store(p, v, __ATOMIC_RELAXED, __HIP_MEMORY_SCOPE_AGENT);
}
__device__ __forceinline__ unsigned auload(const unsigned* p) {
    return __hip_atomic_load(p, __ATOMIC_RELAXED, __HIP_MEMORY_SCOPE_AGENT);
}
__device__ __forceinline__ void austore(unsigned* p, unsigned v) {
    __hip_atomic_store(p, v, __ATOMIC_RELAXED, __HIP_MEMORY_SCOPE_AGENT);
}
// monotonic f32<->u32 key for atomicMax-based max pooling
__device__ __forceinline__ unsigned enc(float f) {
    unsigned b = __float_as_uint(f);
    return (b & 0x80000000u) ? ~b : (b | 0x80000000u);
}
__device__ __forceinline__ float dec(unsigned k) {
    unsigned b = (k & 0x80000000u) ? (k & 0x7FFFFFFFu) : ~k;
    return __uint_as_float(b);
}

// fence-free grid barrier on monotone counter (epoch scheme -> replay safe)
__device__ __forceinline__ void gsync(unsigned base, unsigned k, bool spin) {
    asm volatile("s_waitcnt vmcnt(0) lgkmcnt(0)" ::: "memory");
    __syncthreads();
    if (threadIdx.x == 0) {
        unsigned ret = __hip_atomic_fetch_add(&g_bar, 1u, __ATOMIC_RELAXED, __HIP_MEMORY_SCOPE_AGENT);
        if (k == NSYNC && ret == base + NSYNC * NBLK - 1u)
            __hip_atomic_store(&g_epoch, base / (NSYNC * NBLK) + 1u,
                               __ATOMIC_RELAXED, __HIP_MEMORY_SCOPE_AGENT);
        if (spin) {
            unsigned target = base + k * NBLK;
            unsigned spins = 0;
            while (__hip_atomic_load(&g_bar, __ATOMIC_RELAXED, __HIP_MEMORY_SCOPE_AGENT) < target) {
                if (++spins > (1u << 22)) break;  // hang safety
                __builtin_amdgcn_s_sleep(1);
            }
        }
    }
    __syncthreads();
}

struct Args {
    const float *x; const int *ei; const float *ea;
    const float *w0, *b0, *g0, *be0;
    const float *w1, *b1, *g1, *be1;
    const float *w2a, *b2a, *g2a, *be2a;
    const float *w2b, *b2b, *g2b, *be2b;
    const float *w3a, *b3a, *w3b, *b3b;
    const float *p1_wrel, *p1_wroot, *p1_b, *p2_wrel, *p2_wroot, *p2_b;
    float *psum1, *psum2a, *psum2b;
    float *t1, *sc1, *t2, *sc2, *bn1c, *bn2bc;
    int *rk_g, *nsrc, *ndst; float *new_ew;
    unsigned *gmax;
    float *out;
};

__global__ __launch_bounds__(256) void k_mega(Args a) {
    __shared__ float h1t[NT][64];      // owned raw h1 rows
    __shared__ float h2at[NT][128];    // owned raw h2a rows (survivors)
    __shared__ float h2bt[NT][200];    // owned raw h2b rows (survivors)
    __shared__ float ybuf[NT][68];     // staging: y0 / xp / lin2b x-tiles
    __shared__ float wflat[4224];      // weight k-tile staging (16.9 KB)
    __shared__ float stage1k[N0];      // score/t staging (4 KB)
    __shared__ float bnc[2][200];      // BN scale/shift
    __shared__ float red[256], red2[256];
    __shared__ int rloc[NT], surv_j[NT], surv_r[NT];
    __shared__ float th[NT];
    __shared__ int ns;
    __shared__ unsigned sh_base;

    const int b = blockIdx.x, t = threadIdx.x;
    const int lane = t & 63, wv = t >> 6;
    const int nb = b * NT;
    const int nn = (N0 - nb) < 0 ? 0 : ((N0 - nb) < NT ? (N0 - nb) : NT);

    if (t == 0)
        sh_base = __hip_atomic_load(&g_epoch, __ATOMIC_RELAXED, __HIP_MEMORY_SCOPE_AGENT) * (NSYNC * NBLK);
    __syncthreads();
    const unsigned base = sh_base;

    // ================= P1: lin0+lin1, tile local ======================
    {
        if (b == 0 && t < 200) austore(&a.gmax[t], 0u);  // re-init each replay
        // redundant BN0 stats (cached input reads, pure VALU)
        {
            const int c = lane, slot = wv;
            float wa = a.w0[c * 3], wb_ = a.w0[c * 3 + 1], wc_ = a.w0[c * 3 + 2], bb = a.b0[c];
            float s = 0.f, q = 0.f;
            for (int n = slot; n < N0; n += 4) {
                float h = fmaf(wa, a.x[n * 3], fmaf(wb_, a.x[n * 3 + 1], fmaf(wc_, a.x[n * 3 + 2], bb)));
                s += h; q += h * h;
            }
            red[t] = s; red2[t] = q;
            __syncthreads();
            if (t < 64) {
                float S = red[t] + red[t + 64] + red[t + 128] + red[t + 192];
                float Q = red2[t] + red2[t + 64] + red2[t + 128] + red2[t + 192];
                float mu = S * (1.f / N0);
                float var = Q * (1.f / N0) - mu * mu;
                float sv = a.g0[t] * rsqrtf(var + EPS);
                bnc[0][t] = sv; bnc[1][t] = a.be0[t] - mu * sv;
            }
            __syncthreads();
        }
        // y0 tile (recompute h0 + BN0 relu)
        for (int e = t; e < NT * 64; e += 256) {
            int r = e >> 6, c = e & 63;
            float v = 0.f;
            if (r < nn) {
                int n = nb + r;
                float h = fmaf(a.w0[c * 3], a.x[n * 3],
                          fmaf(a.w0[c * 3 + 1], a.x[n * 3 + 1],
                          fmaf(a.w0[c * 3 + 2], a.x[n * 3 + 2], a.b0[c])));
                v = bnr(h, bnc[0][c], bnc[1][c]);
            }
            ybuf[r][c] = v;
        }
        // stage w1 [64][65]
        for (int e = t; e < 64 * 64; e += 256)
            wflat[(e >> 6) * 65 + (e & 63)] = a.w1[e];
        __syncthreads();
        // lin1: c=lane, slot=wv owns rows slot*4..+4
        {
            const int c = lane, slot = wv;
            float bb1 = a.b1[c];
            float acc[4] = {bb1, bb1, bb1, bb1};
            for (int k = 0; k < 64; ++k) {
                float w = wflat[c * 65 + k];
                #pragma unroll
                for (int i = 0; i < 4; ++i) acc[i] = fmaf(ybuf[slot * 4 + i][k], w, acc[i]);
            }
            float s = 0.f, q = 0.f;
            #pragma unroll
            for (int i = 0; i < 4; ++i) {
                int r = slot * 4 + i;
                h1t[r][c] = acc[i];
                if (r < nn) { s += acc[i]; q += acc[i] * acc[i]; }
            }
            __syncthreads();
            red[t] = s; red2[t] = q;
            __syncthreads();
            if (t < 64) {
                astore(&a.psum1[b * 128 + t],      red[t] + red[t + 64] + red[t + 128] + red[t + 192]);
                astore(&a.psum1[b * 128 + 64 + t], red2[t] + red2[t + 64] + red2[t + 128] + red2[t + 192]);
            }
        }
    }
    gsync(base, 1, true);

    // ================= P2: BN1, t1 + sc1-root (own nodes) ==============
    {
        if (t < 128) {
            float s = 0.f;
            for (int i = 0; i < 64; ++i) s += aload(&a.psum1[i * 128 + t]);
            red[t] = s;
        }
        __syncthreads();
        if (t < 64) {
            float mu = red[t] * (1.f / N0);
            float var = red[64 + t] * (1.f / N0) - mu * mu;
            float sv = a.g1[t] * rsqrtf(var + EPS);
            bnc[0][t] = sv; bnc[1][t] = a.be1[t] - mu * sv;
            if (b == 0) { astore(&a.bn1c[t], sv); astore(&a.bn1c[64 + t], bnc[1][t]); }
        }
        __syncthreads();
        for (int j = wv; j < nn; j += 4) {
            float v = bnr(h1t[j][lane], bnc[0][lane], bnc[1][lane]);
            float dr = v * a.p1_wrel[lane], dt = v * a.p1_wroot[lane];
            #pragma unroll
            for (int m = 32; m >= 1; m >>= 1) {
                dr += __shfl_xor(dr, m, 64);
                dt += __shfl_xor(dt, m, 64);
            }
            if (lane == 0) { astore(&a.t1[nb + j], dr); astore(&a.sc1[nb + j], dt + a.p1_b[0]); }
        }
    }
    gsync(base, 2, true);

    // ================= P3: scatter1 (own 500 edges) ====================
    {
        for (int i = t; i < N0; i += 256) stage1k[i] = aload(&a.t1[i]);
        __syncthreads();
        for (int e = b * 500 + t; e < b * 500 + 500; e += 256) {
            float w = a.ea[e];
            if (w != 0.f) atomicAdd(&a.sc1[a.ei[NE + e]], w * stage1k[a.ei[e]]);
        }
    }
    gsync(base, 3, true);

    // ========== P4: rank1, select, xp local, lin2a local ===============
    {
        for (int i = t; i < N0; i += 256) stage1k[i] = aload(&a.sc1[i]);
        if (t < 128) red[t] = aload(&a.bn1c[t]);  // sc in [0:64), sh in [64:128)
        __syncthreads();
        // rank own nodes (wave-per-node)
        for (int j = wv; j < nn; j += 4) {
            float s = stage1k[nb + j];
            int r = 0;
            for (int m = lane; m < N0; m += 64) {
                float smv = stage1k[m];
                r += (smv > s) || (smv == s && m < nb + j);
            }
            #pragma unroll
            for (int msk = 32; msk >= 1; msk >>= 1) r += __shfl_xor(r, msk, 64);
            if (lane == 0) { aistore(&a.rk_g[nb + j], r); rloc[j] = r; }
        }
        __syncthreads();
        if (t == 0) {
            int c_ = 0;
            for (int j = 0; j < nn; ++j)
                if (rloc[j] < NK1) { surv_j[c_] = j; surv_r[c_] = rloc[j]; ++c_; }
            ns = c_;
        }
        __syncthreads();
        if (t < ns) th[t] = tanhf(stage1k[nb + surv_j[t]]);
        __syncthreads();
        // xp rows into ybuf
        for (int e = t; e < NT * 64; e += 256) {
            int i = e >> 6, c = e & 63;
            ybuf[i][c] = (i < ns) ? bnr(h1t[surv_j[i]][c], red[c], red[64 + c]) * th[i] : 0.f;
        }
        __syncthreads();
        // lin2a: c=t&127, half owns rows half*8..+8; k-tiled weights
        {
            const int c = t & 127, half = t >> 7;
            float bb2 = a.b2a[c];
            float acc[8] = {bb2, bb2, bb2, bb2, bb2, bb2, bb2, bb2};
            for (int kt = 0; kt < 2; ++kt) {
                __syncthreads();
                for (int e = t; e < 128 * 32; e += 256)
                    wflat[(e >> 5) * 33 + (e & 31)] = a.w2a[(e >> 5) * 64 + kt * 32 + (e & 31)];
                __syncthreads();
                for (int k = 0; k < 32; ++k) {
                    float w = wflat[c * 33 + k];
                    #pragma unroll
                    for (int i = 0; i < 8; ++i)
                        acc[i] = fmaf(ybuf[half * 8 + i][kt * 32 + k], w, acc[i]);
                }
            }
            float s = 0.f, q = 0.f;
            #pragma unroll
            for (int i = 0; i < 8; ++i) {
                int r = half * 8 + i;
                h2at[r][c] = acc[i];
                if (r < ns) { s += acc[i]; q += acc[i] * acc[i]; }
            }
            __syncthreads();
            red[t] = s; red2[t] = q;
            __syncthreads();
            if (t < 128) {
                astore(&a.psum2a[b * 256 + t],       red[t] + red[t + 128]);
                astore(&a.psum2a[b * 256 + 128 + t], red2[t] + red2[t + 128]);
            }
        }
    }
    gsync(base, 4, true);

    // ========== P5: edge remap + BN2a + lin2b local ====================
    {
        for (int e = b * 500 + t; e < b * 500 + 500; e += 256) {
            int s_ = a.ei[e], d_ = a.ei[NE + e];
            int rs_ = aiload(&a.rk_g[s_]), rd_ = aiload(&a.rk_g[d_]);
            bool v = (rs_ < NK1) && (rd_ < NK1);
            aistore(&a.nsrc[e], v ? rs_ : 0);
            aistore(&a.ndst[e], v ? rd_ : 0);
            astore(&a.new_ew[e], v ? a.ea[e] : 0.f);
        }
        {
            float s = 0.f;
            for (int i = 0; i < 64; ++i) s += aload(&a.psum2a[i * 256 + t]);
            red[t] = s;
        }
        __syncthreads();
        if (t < 128) {
            float mu = red[t] * (1.f / NK1);
            float var = red[128 + t] * (1.f / NK1) - mu * mu;
            float sv = a.g2a[t] * rsqrtf(var + EPS);
            bnc[0][t] = sv; bnc[1][t] = a.be2a[t] - mu * sv;
        }
        __syncthreads();
        // lin2b: thread t<200 computes all 16 rows; 8 k-tiles of 16
        float acc2[16];
        {
            float bb = (t < 200) ? a.b2b[t] : 0.f;
            #pragma unroll
            for (int i = 0; i < 16; ++i) acc2[i] = bb;
        }
        for (int kt = 0; kt < 8; ++kt) {
            __syncthreads();
            for (int e = t; e < 200 * 16; e += 256)
                wflat[(e >> 4) * 17 + (e & 15)] = a.w2b[(e >> 4) * 128 + kt * 16 + (e & 15)];
            {
                int i = t >> 4, k = t & 15;
                ybuf[i][k] = (i < ns)
                    ? bnr(h2at[i][kt * 16 + k], bnc[0][kt * 16 + k], bnc[1][kt * 16 + k]) : 0.f;
            }
            __syncthreads();
            if (t < 200) {
                for (int k = 0; k < 16; ++k) {
                    float w = wflat[t * 17 + k];
                    #pragma unroll
                    for (int i = 0; i < 16; ++i) acc2[i] = fmaf(ybuf[i][k], w, acc2[i]);
                }
            }
        }
        if (t < 200) {
            float s = 0.f, q = 0.f;
            #pragma unroll
            for (int i = 0; i < 16; ++i) {
                h2bt[i][t] = acc2[i];
                if (i < ns) { s += acc2[i]; q += acc2[i] * acc2[i]; }
            }
            astore(&a.psum2b[b * 400 + t], s);
            astore(&a.psum2b[b * 400 + 200 + t], q);
        }
    }
    gsync(base, 5, true);

    // ========== P6: BN2b + score2 (own survivors) ======================
    {
        for (int idx = t; idx < 400; idx += 256) {
            float s = 0.f;
            for (int i = 0; i < 64; ++i) s += aload(&a.psum2b[i * 400 + idx]);
            stage1k[idx] = s;
        }
        __syncthreads();
        if (t < 200) {
            float mu = stage1k[t] * (1.f / NK1);
            float var = stage1k[200 + t] * (1.f / NK1) - mu * mu;
            float sv = a.g2b[t] * rsqrtf(var + EPS);
            bnc[0][t] = sv; bnc[1][t] = a.be2b[t] - mu * sv;
            if (b == 0) { astore(&a.bn2bc[t], sv); astore(&a.bn2bc[200 + t], bnc[1][t]); }
        }
        __syncthreads();
        for (int i = wv; i < ns; i += 4) {
            float dr = 0.f, dt = 0.f;
            #pragma unroll
            for (int j = 0; j < 4; ++j) {
                int ch = lane + 64 * j;
                if (ch < 200) {
                    float v = bnr(h2bt[i][ch], bnc[0][ch], bnc[1][ch]);
                    dr = fmaf(v, a.p2_wrel[ch], dr);
                    dt = fmaf(v, a.p2_wroot[ch], dt);
                }
            }
            #pragma unroll
            for (int m = 32; m >= 1; m >>= 1) {
                dr += __shfl_xor(dr, m, 64);
                dt += __shfl_xor(dt, m, 64);
            }
            if (lane == 0) {
                int r = surv_r[i];
                astore(&a.t2[r], dr);
                astore(&a.sc2[r], dt + a.p2_b[0]);
            }
        }
    }
    gsync(base, 6, true);

    // ========== P7: scatter2 (own 500 remapped edges) ==================
    {
        for (int i = t; i < NK1; i += 256) stage1k[i] = aload(&a.t2[i]);
        __syncthreads();
        for (int e = b * 500 + t; e < b * 500 + 500; e += 256) {
            float w = aload(&a.new_ew[e]);
            if (w != 0.f)
                atomicAdd(&a.sc2[aiload(&a.ndst[e])], w * stage1k[aiload(&a.nsrc[e])]);
        }
    }
    gsync(base, 7, true);

    // ========== P8: rank2 + max-pool contribution (atomicMax) ==========
    {
        for (int i = t; i < NK1; i += 256) stage1k[i] = aload(&a.sc2[i]);
        if (t < 200) bnc[0][t] = aload(&a.bn2bc[t]);
        else if (t < 400) bnc[1][t - 200] = aload(&a.bn2bc[t]);
        __syncthreads();
        for (int i = wv; i < ns; i += 4) {
            int r = surv_r[i];
            float s = stage1k[r];
            int r2 = 0;
            for (int m = lane; m < NK1; m += 64) {
                float smv = stage1k[m];
                r2 += (smv > s) || (smv == s && m < r);
            }
            #pragma unroll
            for (int msk = 32; msk >= 1; msk >>= 1) r2 += __shfl_xor(r2, msk, 64);
            if (r2 < NK2) {
                float tn = tanhf(s);
                #pragma unroll
                for (int j = 0; j < 4; ++j) {
                    int ch = lane + 64 * j;
                    if (ch < 200) {
                        float v = bnr(h2bt[i][ch], bnc[0][ch], bnc[1][ch]) * tn;
                        atomicMax(&a.gmax[ch], enc(v));
                    }
                }
            }
        }
    }
    gsync(base, 8, b == 0);  // non-zero blocks arrive and exit

    // ========== P9 (block 0): decode gmax + mlp_third + log_softmax ====
    if (b == 0) {
        if (t < 200) stage1k[t] = dec(auload(&a.gmax[t]));
        __syncthreads();
        for (int it = 0; it < 32; ++it) {
            int r = wv + 4 * it;
            float p = 0.f;
            #pragma unroll
            for (int j = 0; j < 4; ++j) {
                int ch = lane + 64 * j;
                if (ch < 200) p = fmaf(a.w3a[r * 200 + ch], stage1k[ch], p);
            }
            #pragma unroll
            for (int m = 32; m >= 1; m >>= 1) p += __shfl_xor(p, m, 64);
            if (lane == 0) red[r] = fmaxf(p + a.b3a[r], 0.f);
        }
        __syncthreads();
        if (t < 128) {
            int ow = t >> 6;
            float p = a.w3b[ow * 128 + lane] * red[lane]
                    + a.w3b[ow * 128 + 64 + lane] * red[64 + lane];
            #pragma unroll
            for (int m = 32; m >= 1; m >>= 1) p += __shfl_xor(p, m, 64);
            if (lane == 0) red2[ow] = fmaxf(p + a.b3b[ow], 0.f);
        }
        __syncthreads();
        if (t == 0) {
            float m = fmaxf(red2[0], red2[1]);
            float l = m + logf(expf(red2[0] - m) + expf(red2[1] - m));
            a.out[0] = red2[0] - l;
            a.out[1] = red2[1] - l;
        }
    }
}

extern "C" void kernel_launch(void* const* d_in, const int* in_sizes, int n_in,
                              void* d_out, int out_size, void* d_ws, size_t ws_size,
                              hipStream_t stream) {
    float* ws = (float*)d_ws;

    Args a;
    a.x    = (const float*)d_in[0];
    a.ei   = (const int*)d_in[1];
    a.ea   = (const float*)d_in[2];
    a.w0   = (const float*)d_in[3];  a.b0   = (const float*)d_in[4];
    a.g0   = (const float*)d_in[5];  a.be0  = (const float*)d_in[6];
    a.w1   = (const float*)d_in[7];  a.b1   = (const float*)d_in[8];
    a.g1   = (const float*)d_in[9];  a.be1  = (const float*)d_in[10];
    a.w2a  = (const float*)d_in[11]; a.b2a  = (const float*)d_in[12];
    a.g2a  = (const float*)d_in[13]; a.be2a = (const float*)d_in[14];
    a.w2b  = (const float*)d_in[15]; a.b2b  = (const float*)d_in[16];
    a.g2b  = (const float*)d_in[17]; a.be2b = (const float*)d_in[18];
    a.w3a  = (const float*)d_in[19]; a.b3a  = (const float*)d_in[20];
    a.w3b  = (const float*)d_in[21]; a.b3b  = (const float*)d_in[22];
    a.p1_wrel  = (const float*)d_in[23];
    a.p1_wroot = (const float*)d_in[24];
    a.p1_b     = (const float*)d_in[25];
    a.p2_wrel  = (const float*)d_in[26];
    a.p2_wroot = (const float*)d_in[27];
    a.p2_b     = (const float*)d_in[28];

    a.psum1  = ws;                       // 8192   (64 x 128)
    a.psum2a = ws + 8192;                // 16384  (64 x 256)
    a.psum2b = ws + 24576;               // 25600  (64 x 400)
    a.t1     = ws + 50176;               // 1000
    a.sc1    = ws + 51176;               // 1000
    a.t2     = ws + 52176;               // 500
    a.sc2    = ws + 52676;               // 500
    a.bn1c   = ws + 53176;               // 128
    a.bn2bc  = ws + 53304;               // 400
    a.rk_g   = (int*)(ws + 53704);       // 1000
    a.nsrc   = (int*)(ws + 54704);       // 32000
    a.ndst   = (int*)(ws + 86704);       // 32000
    a.new_ew = ws + 118704;              // 32000
    a.gmax   = (unsigned*)(ws + 150704); // 200
    a.out    = (float*)d_out;

    k_mega<<<NBLK, 256, 0, stream>>>(a);
}